// Round 1
// baseline (2497.235 us; speedup 1.0000x reference)
//
#include <hip/hip_runtime.h>

#define NNODES 50000
#define FDIM 128

typedef float f4 __attribute__((ext_vector_type(4)));

// ---- degree histogram over dst (self loops handled as +1 in scan) ----
__global__ __launch_bounds__(256) void k_count(const int* __restrict__ dst,
                                               int* __restrict__ cnt, int E) {
    int e = blockIdx.x * 256 + threadIdx.x;
    if (e < E) atomicAdd(&cnt[dst[e]], 1);
}

// ---- single-block exclusive scan over cnt -> rowptr; dinv = rsqrt(1+cnt) ----
__global__ __launch_bounds__(1024) void k_scan(const int* __restrict__ cnt,
                                               int* __restrict__ rowptr,
                                               float* __restrict__ dinv, int N) {
    __shared__ int sums[1024];
    int t = threadIdx.x;
    int CH = (N + 1023) >> 10;           // 49
    int b0 = t * CH;
    int b1 = min(b0 + CH, N);
    int s = 0;
    for (int i = b0; i < b1; ++i) s += cnt[i];
    sums[t] = s;
    __syncthreads();
    // Hillis-Steele inclusive scan
    for (int off = 1; off < 1024; off <<= 1) {
        int v = (t >= off) ? sums[t - off] : 0;
        __syncthreads();
        sums[t] += v;
        __syncthreads();
    }
    int run = (t == 0) ? 0 : sums[t - 1];
    for (int i = b0; i < b1; ++i) {
        rowptr[i] = run;
        int c = cnt[i];
        dinv[i] = rsqrtf(1.0f + (float)c);   // deg includes self loop
        run += c;
    }
    if (b1 == N) rowptr[N] = run;  // all qualifying threads write the same total (=E)
}

// ---- CSR fill: col[rowptr[d] + slot] = src ----
__global__ __launch_bounds__(256) void k_fill(const int* __restrict__ src,
                                              const int* __restrict__ dst,
                                              const int* __restrict__ rowptr,
                                              int* __restrict__ fill,
                                              int* __restrict__ col, int E) {
    int e = blockIdx.x * 256 + threadIdx.x;
    if (e < E) {
        int d = dst[e];
        int slot = atomicAdd(&fill[d], 1);
        col[rowptr[d] + slot] = src[e];
    }
}

// ---- f32 GEMM: C[nrows,128] = A[nrows,128] @ W[128,128] ----
// block = 256 threads, tile = 32 rows x 128 cols, thread = 4 rows x 4 cols.
// W fully staged in LDS (64 KB) + 32x128 x-tile (16 KB) -> 2 blocks/CU.
__global__ __launch_bounds__(256) void k_gemm(const float* __restrict__ A,
                                              const float* __restrict__ W,
                                              float* __restrict__ C, int nrows) {
    __shared__ float ws[128 * 128];
    __shared__ float xs[32 * 128];
    int t = threadIdx.x;
    int rb = blockIdx.x * 32;

    // stage W: 4096 float4s
    const f4* W4 = (const f4*)W;
    f4* ws4 = (f4*)ws;
#pragma unroll
    for (int i = 0; i < 16; ++i) ws4[t + i * 256] = W4[t + i * 256];

    // stage A rows rb..rb+31 (row clamped; junk rows never stored)
    f4* xs4 = (f4*)xs;
#pragma unroll
    for (int i = 0; i < 4; ++i) {
        int f = t + i * 256;          // float4 index in tile, 0..1023
        int row = f >> 5;             // 32 float4 per row
        int cf = f & 31;
        int rg = rb + row;
        if (rg > nrows - 1) rg = nrows - 1;
        xs4[f] = ((const f4*)(A + (size_t)rg * FDIM))[cf];
    }
    __syncthreads();

    int ctid = t & 31;
    int rtid = t >> 5;
    int c0 = ctid * 4;

    f4 acc[4];
#pragma unroll
    for (int j = 0; j < 4; ++j)
#pragma unroll
        for (int c = 0; c < 4; ++c) acc[j][c] = 0.0f;

    for (int k = 0; k < 128; k += 4) {
        f4 xv[4], wv[4];
#pragma unroll
        for (int j = 0; j < 4; ++j)
            xv[j] = *(const f4*)&xs[(rtid + 8 * j) * 128 + k];
#pragma unroll
        for (int kk = 0; kk < 4; ++kk)
            wv[kk] = *(const f4*)&ws[(k + kk) * 128 + c0];
#pragma unroll
        for (int j = 0; j < 4; ++j)
#pragma unroll
            for (int kk = 0; kk < 4; ++kk)
                acc[j] += xv[j][kk] * wv[kk];
    }

#pragma unroll
    for (int j = 0; j < 4; ++j) {
        int rg = rb + rtid + 8 * j;
        if (rg < nrows) *(f4*)(C + (size_t)rg * FDIM + c0) = acc[j];
    }
}

// ---- aggregation: one wave per node, lane = 2 features (float2) ----
// out[n] = dinv[n]*( dinv[n]*h[n] + sum_{s in nbrs(n)} dinv[s]*h[s] ) + b
__global__ __launch_bounds__(256) void k_agg(const float* __restrict__ h,
                                             const int* __restrict__ rowptr,
                                             const int* __restrict__ col,
                                             const float* __restrict__ dinv,
                                             const float* __restrict__ bias,
                                             float* __restrict__ out,
                                             float* __restrict__ out2, int relu) {
    int gw = (blockIdx.x * 256 + threadIdx.x) >> 6;
    int lane = threadIdx.x & 63;
    if (gw >= NNODES) return;
    int n = gw;
    int beg = rowptr[n];
    int end = rowptr[n + 1];
    float di = dinv[n];

    const float2* h2 = (const float2*)h;
    float2 hv = h2[(size_t)n * 64 + lane];
    float ax = di * hv.x;
    float ay = di * hv.y;

    for (int base = beg; base < end; base += 64) {
        int rem = end - base;
        int cv = 0;
        float wv = 0.0f;
        if (lane < rem) {
            cv = col[base + lane];
            wv = dinv[cv];
        }
        int cnt = rem < 64 ? rem : 64;
        for (int j = 0; j < cnt; ++j) {
            int s = __shfl(cv, j);
            float w = __shfl(wv, j);
            float2 hh = h2[(size_t)s * 64 + lane];
            ax = fmaf(w, hh.x, ax);
            ay = fmaf(w, hh.y, ay);
        }
    }

    float2 bv = ((const float2*)bias)[lane];
    float ox = di * ax + bv.x;
    float oy = di * ay + bv.y;
    if (relu) {
        ox = fmaxf(ox, 0.0f);
        oy = fmaxf(oy, 0.0f);
    }
    float2 o;
    o.x = ox;
    o.y = oy;
    ((float2*)out)[(size_t)n * 64 + lane] = o;
    if (out2) ((float2*)out2)[(size_t)n * 64 + lane] = o;
}

extern "C" void kernel_launch(void* const* d_in, const int* in_sizes, int n_in,
                              void* d_out, int out_size, void* d_ws, size_t ws_size,
                              hipStream_t stream) {
    const float* x  = (const float*)d_in[0];
    const int*   ei = (const int*)d_in[1];
    const float* W1 = (const float*)d_in[2];
    const float* b1 = (const float*)d_in[3];
    const float* W2 = (const float*)d_in[4];
    const float* b2 = (const float*)d_in[5];
    const float* W3 = (const float*)d_in[6];
    const float* b3 = (const float*)d_in[7];
    int E = in_sizes[1] / 2;
    const int* srcp = ei;
    const int* dstp = ei + E;
    float* outf = (float*)d_out;

    // workspace layout
    float* bufA  = (float*)d_ws;                          // 6.4M floats (25.6 MB)
    int*   cnt   = (int*)(bufA + (size_t)NNODES * FDIM);  // N ints
    int*   fill  = cnt + NNODES;                          // N ints
    int*   rowptr= fill + NNODES;                         // N+1 ints
    float* dinv  = (float*)(rowptr + NNODES + 1);         // N floats
    int*   col   = (int*)(dinv + NNODES);                 // E ints
    float* bufB  = outf;  // first half of d_out doubles as ping-pong scratch

    // zero cnt + fill (adjacent)
    hipMemsetAsync(cnt, 0, sizeof(int) * 2 * NNODES, stream);

    int eb = (E + 255) / 256;
    k_count<<<eb, 256, 0, stream>>>(dstp, cnt, E);
    k_scan<<<1, 1024, 0, stream>>>(cnt, rowptr, dinv, NNODES);
    k_fill<<<eb, 256, 0, stream>>>(srcp, dstp, rowptr, fill, col, E);

    int gb = (NNODES + 31) / 32;               // 1563 GEMM blocks
    int ab = (NNODES * 64 + 255) / 256;        // 12500 agg blocks (1 wave/node)

    k_gemm<<<gb, 256, 0, stream>>>(x, W1, bufA, NNODES);
    k_agg<<<ab, 256, 0, stream>>>(bufA, rowptr, col, dinv, b1, bufB, nullptr, 1);
    k_gemm<<<gb, 256, 0, stream>>>(bufB, W2, bufA, NNODES);
    k_agg<<<ab, 256, 0, stream>>>(bufA, rowptr, col, dinv, b2, bufB, nullptr, 1);
    k_gemm<<<gb, 256, 0, stream>>>(bufB, W3, bufA, NNODES);
    k_agg<<<ab, 256, 0, stream>>>(bufA, rowptr, col, dinv, b3, outf,
                                  outf + (size_t)NNODES * FDIM, 0);
}

// Round 2
// 505.595 us; speedup vs baseline: 4.9392x; 4.9392x over previous
//
#include <hip/hip_runtime.h>

#define NNODES 50000
#define FDIM 128

typedef float f4 __attribute__((ext_vector_type(4)));

// ---- degree histogram over dst (self loops handled as +1 in scan) ----
__global__ __launch_bounds__(256) void k_count(const int* __restrict__ dst,
                                               int* __restrict__ cnt, int E) {
    int e = blockIdx.x * 256 + threadIdx.x;
    if (e < E) atomicAdd(&cnt[dst[e]], 1);
}

// ---- single-block exclusive scan over cnt -> rowptr; dinv = rsqrt(1+cnt) ----
__global__ __launch_bounds__(1024) void k_scan(const int* __restrict__ cnt,
                                               int* __restrict__ rowptr,
                                               float* __restrict__ dinv, int N) {
    __shared__ int sums[1024];
    int t = threadIdx.x;
    int CH = (N + 1023) >> 10;           // 49
    int b0 = t * CH;
    int b1 = min(b0 + CH, N);
    int s = 0;
    for (int i = b0; i < b1; ++i) s += cnt[i];
    sums[t] = s;
    __syncthreads();
    for (int off = 1; off < 1024; off <<= 1) {
        int v = (t >= off) ? sums[t - off] : 0;
        __syncthreads();
        sums[t] += v;
        __syncthreads();
    }
    int run = (t == 0) ? 0 : sums[t - 1];
    for (int i = b0; i < b1; ++i) {
        rowptr[i] = run;
        int c = cnt[i];
        dinv[i] = rsqrtf(1.0f + (float)c);   // deg includes self loop
        run += c;
    }
    if (b1 == N) rowptr[N] = run;
}

// ---- CSR fill: col[rowptr[d] + slot] = src ----
__global__ __launch_bounds__(256) void k_fill(const int* __restrict__ src,
                                              const int* __restrict__ dst,
                                              const int* __restrict__ rowptr,
                                              int* __restrict__ fill,
                                              int* __restrict__ col, int E) {
    int e = blockIdx.x * 256 + threadIdx.x;
    if (e < E) {
        int d = dst[e];
        int slot = atomicAdd(&fill[d], 1);
        col[rowptr[d] + slot] = src[e];
    }
}

// ---- f32 GEMM: C[nrows,128] = A[nrows,128] @ W[128,128] ----
// 256 thr, 64-row x 128-col tile. Thread = 8 rows x 4 cols (acc = 32 VGPR).
// LDS: A-tile 32 KB + W-chunk (32 k-rows) 16 KB = 48 KB -> 3 blocks/CU.
// #pragma unroll 1 on outer loops: round-1 kernel spilled ~1.5 KB/thread
// (1.6 GB scratch traffic) from full k-loop unroll at 256-VGPR cap.
__global__ __launch_bounds__(256, 3) void k_gemm(const float* __restrict__ A,
                                                 const float* __restrict__ W,
                                                 float* __restrict__ C, int nrows) {
    __shared__ float xs[64 * 128];   // 32 KB
    __shared__ float ws[32 * 128];   // 16 KB
    f4* xs4 = (f4*)xs;
    f4* ws4 = (f4*)ws;
    const f4* A4 = (const f4*)A;
    const f4* W4 = (const f4*)W;
    int t = threadIdx.x;
    int rb = blockIdx.x * 64;

    // stage A tile: 2048 f4, lane-consecutive (coalesced, conflict-free)
#pragma unroll
    for (int i = 0; i < 8; ++i) {
        int f = i * 256 + t;
        int row = f >> 5;                 // 32 f4 per row
        int rg = rb + row;
        if (rg > nrows - 1) rg = nrows - 1;
        xs4[f] = A4[(size_t)rg * 32 + (f & 31)];
    }

    int ctid = t & 31;                    // col group, c0 = ctid*4
    int rtid = t >> 5;                    // 0..7; rows rtid + 8j

    f4 acc[8];
#pragma unroll
    for (int j = 0; j < 8; ++j) acc[j] = (f4)0.0f;

#pragma unroll 1
    for (int kc = 0; kc < 4; ++kc) {
        __syncthreads();                  // ws reuse fence (also covers xs at kc=0)
#pragma unroll
        for (int i = 0; i < 4; ++i) {
            int f = i * 256 + t;
            ws4[f] = W4[kc * 1024 + f];   // W rows kc*32 .. kc*32+31
        }
        __syncthreads();
#pragma unroll 1
        for (int k = 0; k < 32; k += 4) {
            f4 wv[4];
#pragma unroll
            for (int kk = 0; kk < 4; ++kk)
                wv[kk] = ws4[(k + kk) * 32 + ctid];
            int kg = (kc * 32 + k) >> 2;  // f4 index along a row
#pragma unroll
            for (int j = 0; j < 8; ++j) {
                f4 xv = xs4[(rtid + 8 * j) * 32 + kg];
#pragma unroll
                for (int kk = 0; kk < 4; ++kk)
                    acc[j] += xv[kk] * wv[kk];
            }
        }
    }

#pragma unroll
    for (int j = 0; j < 8; ++j) {
        int rg = rb + rtid + 8 * j;
        if (rg < nrows)
            *((f4*)C + (size_t)rg * 32 + ctid) = acc[j];
    }
}

// ---- aggregation: one wave per node, lane = 2 features (float2) ----
// out[n] = dinv[n]*( dinv[n]*h[n] + sum_{s in nbrs(n)} dinv[s]*h[s] ) + b
__global__ __launch_bounds__(256) void k_agg(const float* __restrict__ h,
                                             const int* __restrict__ rowptr,
                                             const int* __restrict__ col,
                                             const float* __restrict__ dinv,
                                             const float* __restrict__ bias,
                                             float* __restrict__ out,
                                             float* __restrict__ out2, int relu) {
    int gw = (blockIdx.x * 256 + threadIdx.x) >> 6;
    int lane = threadIdx.x & 63;
    if (gw >= NNODES) return;
    int n = gw;
    int beg = rowptr[n];
    int end = rowptr[n + 1];
    float di = dinv[n];

    const float2* h2 = (const float2*)h;
    float2 hv = h2[(size_t)n * 64 + lane];
    float ax = di * hv.x;
    float ay = di * hv.y;

    for (int base = beg; base < end; base += 64) {
        int rem = end - base;
        int cv = 0;
        float wv = 0.0f;
        if (lane < rem) {
            cv = col[base + lane];
            wv = dinv[cv];
        }
        int cnt = rem < 64 ? rem : 64;
        for (int j = 0; j < cnt; ++j) {
            int s = __shfl(cv, j);
            float w = __shfl(wv, j);
            float2 hh = h2[(size_t)s * 64 + lane];
            ax = fmaf(w, hh.x, ax);
            ay = fmaf(w, hh.y, ay);
        }
    }

    float2 bv = ((const float2*)bias)[lane];
    float ox = di * ax + bv.x;
    float oy = di * ay + bv.y;
    if (relu) {
        ox = fmaxf(ox, 0.0f);
        oy = fmaxf(oy, 0.0f);
    }
    float2 o;
    o.x = ox;
    o.y = oy;
    ((float2*)out)[(size_t)n * 64 + lane] = o;
    if (out2) ((float2*)out2)[(size_t)n * 64 + lane] = o;
}

extern "C" void kernel_launch(void* const* d_in, const int* in_sizes, int n_in,
                              void* d_out, int out_size, void* d_ws, size_t ws_size,
                              hipStream_t stream) {
    const float* x  = (const float*)d_in[0];
    const int*   ei = (const int*)d_in[1];
    const float* W1 = (const float*)d_in[2];
    const float* b1 = (const float*)d_in[3];
    const float* W2 = (const float*)d_in[4];
    const float* b2 = (const float*)d_in[5];
    const float* W3 = (const float*)d_in[6];
    const float* b3 = (const float*)d_in[7];
    int E = in_sizes[1] / 2;
    const int* srcp = ei;
    const int* dstp = ei + E;
    float* outf = (float*)d_out;

    // workspace layout
    float* bufA  = (float*)d_ws;                          // 6.4M floats (25.6 MB)
    int*   cnt   = (int*)(bufA + (size_t)NNODES * FDIM);  // N ints
    int*   fill  = cnt + NNODES;                          // N ints
    int*   rowptr= fill + NNODES;                         // N+1 ints
    float* dinv  = (float*)(rowptr + NNODES + 1);         // N floats
    int*   col   = (int*)(dinv + NNODES);                 // E ints
    float* bufB  = outf;  // first half of d_out doubles as ping-pong scratch

    hipMemsetAsync(cnt, 0, sizeof(int) * 2 * NNODES, stream);

    int eb = (E + 255) / 256;
    k_count<<<eb, 256, 0, stream>>>(dstp, cnt, E);
    k_scan<<<1, 1024, 0, stream>>>(cnt, rowptr, dinv, NNODES);
    k_fill<<<eb, 256, 0, stream>>>(srcp, dstp, rowptr, fill, col, E);

    int gb = (NNODES + 63) / 64;               // 782 GEMM blocks
    int ab = (NNODES * 64 + 255) / 256;        // 12500 agg blocks (1 wave/node)

    k_gemm<<<gb, 256, 0, stream>>>(x, W1, bufA, NNODES);
    k_agg<<<ab, 256, 0, stream>>>(bufA, rowptr, col, dinv, b1, bufB, nullptr, 1);
    k_gemm<<<gb, 256, 0, stream>>>(bufB, W2, bufA, NNODES);
    k_agg<<<ab, 256, 0, stream>>>(bufA, rowptr, col, dinv, b2, bufB, nullptr, 1);
    k_gemm<<<gb, 256, 0, stream>>>(bufB, W3, bufA, NNODES);
    k_agg<<<ab, 256, 0, stream>>>(bufA, rowptr, col, dinv, b3, outf,
                                  outf + (size_t)NNODES * FDIM, 0);
}

// Round 3
// 411.936 us; speedup vs baseline: 6.0622x; 1.2274x over previous
//
#include <hip/hip_runtime.h>

#define NNODES 50000
#define FDIM 128

typedef float f4 __attribute__((ext_vector_type(4)));

// ---- degree histogram over dst (self loops handled as +1 in dinv) ----
__global__ __launch_bounds__(256) void k_count(const int* __restrict__ dst,
                                               int* __restrict__ cnt, int E) {
    int e = blockIdx.x * 256 + threadIdx.x;
    if (e < E) atomicAdd(&cnt[dst[e]], 1);
}

// ---- CSR segment allocation: rowptr[n] = atomicAdd(total, cnt[n]) ----
// Row order in col[] is irrelevant for aggregation, so no prefix scan needed.
// Wave-level shfl scan -> ONE atomic per wave (781 total). Replaces the
// round-2 single-block scan that cost 108 us (1 CU, uncoalesced, 20 barriers).
__global__ __launch_bounds__(256) void k_alloc(const int* __restrict__ cnt,
                                               int* __restrict__ rowptr,
                                               float* __restrict__ dinv,
                                               int* __restrict__ total, int N) {
    int n = blockIdx.x * 256 + threadIdx.x;
    int lane = threadIdx.x & 63;
    int c = (n < N) ? cnt[n] : 0;
    int pref = c;
#pragma unroll
    for (int off = 1; off < 64; off <<= 1) {
        int v = __shfl_up(pref, off);
        if (lane >= off) pref += v;
    }
    int wsum = __shfl(pref, 63);
    int base = 0;
    if (lane == 63) base = atomicAdd(total, wsum);
    base = __shfl(base, 63);
    if (n < N) {
        rowptr[n] = base + pref - c;       // exclusive within wave
        dinv[n] = rsqrtf(1.0f + (float)c); // deg includes self loop
    }
}

// ---- CSR fill: col[rowptr[d] + slot] = src ----
__global__ __launch_bounds__(256) void k_fill(const int* __restrict__ src,
                                              const int* __restrict__ dst,
                                              const int* __restrict__ rowptr,
                                              int* __restrict__ fill,
                                              int* __restrict__ col, int E) {
    int e = blockIdx.x * 256 + threadIdx.x;
    if (e < E) {
        int d = dst[e];
        int slot = atomicAdd(&fill[d], 1);
        col[rowptr[d] + slot] = src[e];
    }
}

// ---- f32 GEMM: C[nrows,128] = A[nrows,128] @ W[128,128] ----
// 256 thr, 64-row x 128-col tile. Thread = 8 rows x 4 cols (acc = 32 VGPR).
// LDS: A-tile 32 KB + W-chunk (32 k-rows) 16 KB = 48 KB -> 3 blocks/CU.
// #pragma unroll 1 on outer loops: round-1 kernel spilled ~1.5 KB/thread
// (1.6 GB scratch traffic) from full k-loop unroll at 256-VGPR cap.
__global__ __launch_bounds__(256, 3) void k_gemm(const float* __restrict__ A,
                                                 const float* __restrict__ W,
                                                 float* __restrict__ C, int nrows) {
    __shared__ float xs[64 * 128];   // 32 KB
    __shared__ float ws[32 * 128];   // 16 KB
    f4* xs4 = (f4*)xs;
    f4* ws4 = (f4*)ws;
    const f4* A4 = (const f4*)A;
    const f4* W4 = (const f4*)W;
    int t = threadIdx.x;
    int rb = blockIdx.x * 64;

#pragma unroll
    for (int i = 0; i < 8; ++i) {
        int f = i * 256 + t;
        int row = f >> 5;                 // 32 f4 per row
        int rg = rb + row;
        if (rg > nrows - 1) rg = nrows - 1;
        xs4[f] = A4[(size_t)rg * 32 + (f & 31)];
    }

    int ctid = t & 31;                    // col group, c0 = ctid*4
    int rtid = t >> 5;                    // 0..7; rows rtid + 8j

    f4 acc[8];
#pragma unroll
    for (int j = 0; j < 8; ++j) acc[j] = (f4)0.0f;

#pragma unroll 1
    for (int kc = 0; kc < 4; ++kc) {
        __syncthreads();                  // ws reuse fence (also covers xs at kc=0)
#pragma unroll
        for (int i = 0; i < 4; ++i) {
            int f = i * 256 + t;
            ws4[f] = W4[kc * 1024 + f];   // W rows kc*32 .. kc*32+31
        }
        __syncthreads();
#pragma unroll 1
        for (int k = 0; k < 32; k += 4) {
            f4 wv[4];
#pragma unroll
            for (int kk = 0; kk < 4; ++kk)
                wv[kk] = ws4[(k + kk) * 32 + ctid];
            int kg = (kc * 32 + k) >> 2;  // f4 index along a row
#pragma unroll
            for (int j = 0; j < 8; ++j) {
                f4 xv = xs4[(rtid + 8 * j) * 32 + kg];
#pragma unroll
                for (int kk = 0; kk < 4; ++kk)
                    acc[j] += xv[kk] * wv[kk];
            }
        }
    }

#pragma unroll
    for (int j = 0; j < 8; ++j) {
        int rg = rb + rtid + 8 * j;
        if (rg < nrows)
            *((f4*)C + (size_t)rg * 32 + ctid) = acc[j];
    }
}

// ---- aggregation: one wave per node, lane = 2 features (float2) ----
// out[n] = dinv[n]*( dinv[n]*h[n] + sum_{s in nbrs(n)} dinv[s]*h[s] ) + b
__global__ __launch_bounds__(256) void k_agg(const float* __restrict__ h,
                                             const int* __restrict__ rowptr,
                                             const int* __restrict__ cnt,
                                             const int* __restrict__ col,
                                             const float* __restrict__ dinv,
                                             const float* __restrict__ bias,
                                             float* __restrict__ out,
                                             float* __restrict__ out2, int relu) {
    int gw = (blockIdx.x * 256 + threadIdx.x) >> 6;
    int lane = threadIdx.x & 63;
    if (gw >= NNODES) return;
    int n = gw;
    int beg = rowptr[n];
    int end = beg + cnt[n];
    float di = dinv[n];

    const float2* h2 = (const float2*)h;
    float2 hv = h2[(size_t)n * 64 + lane];
    float ax = di * hv.x;
    float ay = di * hv.y;

    for (int base = beg; base < end; base += 64) {
        int rem = end - base;
        int cv = 0;
        float wv = 0.0f;
        if (lane < rem) {
            cv = col[base + lane];
            wv = dinv[cv];
        }
        int c = rem < 64 ? rem : 64;
        for (int j = 0; j < c; ++j) {
            int s = __shfl(cv, j);
            float w = __shfl(wv, j);
            float2 hh = h2[(size_t)s * 64 + lane];
            ax = fmaf(w, hh.x, ax);
            ay = fmaf(w, hh.y, ay);
        }
    }

    float2 bv = ((const float2*)bias)[lane];
    float ox = di * ax + bv.x;
    float oy = di * ay + bv.y;
    if (relu) {
        ox = fmaxf(ox, 0.0f);
        oy = fmaxf(oy, 0.0f);
    }
    float2 o;
    o.x = ox;
    o.y = oy;
    ((float2*)out)[(size_t)n * 64 + lane] = o;
    if (out2) ((float2*)out2)[(size_t)n * 64 + lane] = o;
}

extern "C" void kernel_launch(void* const* d_in, const int* in_sizes, int n_in,
                              void* d_out, int out_size, void* d_ws, size_t ws_size,
                              hipStream_t stream) {
    const float* x  = (const float*)d_in[0];
    const int*   ei = (const int*)d_in[1];
    const float* W1 = (const float*)d_in[2];
    const float* b1 = (const float*)d_in[3];
    const float* W2 = (const float*)d_in[4];
    const float* b2 = (const float*)d_in[5];
    const float* W3 = (const float*)d_in[6];
    const float* b3 = (const float*)d_in[7];
    int E = in_sizes[1] / 2;
    const int* srcp = ei;
    const int* dstp = ei + E;
    float* outf = (float*)d_out;

    // workspace layout
    float* bufA  = (float*)d_ws;                          // 6.4M floats (25.6 MB)
    int*   cnt   = (int*)(bufA + (size_t)NNODES * FDIM);  // N ints
    int*   fill  = cnt + NNODES;                          // N ints
    int*   total = fill + NNODES;                         // 1 int
    int*   rowptr= total + 1;                             // N ints
    float* dinv  = (float*)(rowptr + NNODES);             // N floats
    int*   col   = (int*)(dinv + NNODES);                 // E ints
    float* bufB  = outf;  // first half of d_out doubles as ping-pong scratch

    // zero cnt + fill + total (adjacent)
    hipMemsetAsync(cnt, 0, sizeof(int) * (2 * NNODES + 1), stream);

    int eb = (E + 255) / 256;
    int nb = (NNODES + 255) / 256;
    k_count<<<eb, 256, 0, stream>>>(dstp, cnt, E);
    k_alloc<<<nb, 256, 0, stream>>>(cnt, rowptr, dinv, total, NNODES);
    k_fill<<<eb, 256, 0, stream>>>(srcp, dstp, rowptr, fill, col, E);

    int gb = (NNODES + 63) / 64;               // 782 GEMM blocks
    int ab = (NNODES * 64 + 255) / 256;        // 12500 agg blocks (1 wave/node)

    k_gemm<<<gb, 256, 0, stream>>>(x, W1, bufA, NNODES);
    k_agg<<<ab, 256, 0, stream>>>(bufA, rowptr, cnt, col, dinv, b1, bufB, nullptr, 1);
    k_gemm<<<gb, 256, 0, stream>>>(bufB, W2, bufA, NNODES);
    k_agg<<<ab, 256, 0, stream>>>(bufA, rowptr, cnt, col, dinv, b2, bufB, nullptr, 1);
    k_gemm<<<gb, 256, 0, stream>>>(bufB, W3, bufA, NNODES);
    k_agg<<<ab, 256, 0, stream>>>(bufA, rowptr, cnt, col, dinv, b3, outf,
                                  outf + (size_t)NNODES * FDIM, 0);
}

// Round 5
// 382.055 us; speedup vs baseline: 6.5363x; 1.0782x over previous
//
#include <hip/hip_runtime.h>

#define NNODES 50000
#define FDIM 128

typedef float f4 __attribute__((ext_vector_type(4)));
typedef short short8 __attribute__((ext_vector_type(8)));
typedef uint uint4v __attribute__((ext_vector_type(4)));

// ---- degree histogram over dst (self loops handled as +1 in dinv) ----
__global__ __launch_bounds__(256) void k_count(const int* __restrict__ dst,
                                               int* __restrict__ cnt, int E) {
    int e = blockIdx.x * 256 + threadIdx.x;
    if (e < E) atomicAdd(&cnt[dst[e]], 1);
}

// ---- CSR segment allocation: one atomic per wave (order-free CSR) ----
__global__ __launch_bounds__(256) void k_alloc(const int* __restrict__ cnt,
                                               int* __restrict__ rowptr,
                                               float* __restrict__ dinv,
                                               int* __restrict__ total, int N) {
    int n = blockIdx.x * 256 + threadIdx.x;
    int lane = threadIdx.x & 63;
    int c = (n < N) ? cnt[n] : 0;
    int pref = c;
#pragma unroll
    for (int off = 1; off < 64; off <<= 1) {
        int v = __shfl_up(pref, off);
        if (lane >= off) pref += v;
    }
    int wsum = __shfl(pref, 63);
    int base = 0;
    if (lane == 63) base = atomicAdd(total, wsum);
    base = __shfl(base, 63);
    if (n < N) {
        rowptr[n] = base + pref - c;
        dinv[n] = rsqrtf(1.0f + (float)c);
    }
}

// ---- CSR fill ----
__global__ __launch_bounds__(256) void k_fill(const int* __restrict__ src,
                                              const int* __restrict__ dst,
                                              const int* __restrict__ rowptr,
                                              int* __restrict__ fill,
                                              int* __restrict__ col, int E) {
    int e = blockIdx.x * 256 + threadIdx.x;
    if (e < E) {
        int d = dst[e];
        int slot = atomicAdd(&fill[d], 1);
        col[rowptr[d] + slot] = src[e];
    }
}

// ---- split one f32 pair into packed truncated-bf16 hi / lo words ----
__device__ __forceinline__ void split2(float x0, float x1, unsigned& hi, unsigned& lo) {
    unsigned u0 = __float_as_uint(x0), u1 = __float_as_uint(x1);
    unsigned h0 = u0 & 0xffff0000u, h1 = u1 & 0xffff0000u;
    hi = h1 | (h0 >> 16);
    float l0 = x0 - __uint_as_float(h0);
    float l1 = x1 - __uint_as_float(h1);
    lo = (__float_as_uint(l1) & 0xffff0000u) | (__float_as_uint(l0) >> 16);
}

// ---- W pre-split into MFMA B-fragment order (hi 8192 uints, lo 8192 uints) ----
// B-frag for mfma_f32_16x16x32_bf16: lane l, reg j holds W[k][n],
// k=(l>>4)*8+j+32*s, n=t*16+(l&15). Packed record: uint p = ((s*8+t)*64+l)*4+jp
// holds bf16 pair (j=2jp, 2jp+1) -> per-lane ds_read_b128, conflict-free.
__global__ __launch_bounds__(256) void k_prepw(const float* __restrict__ W1,
                                               const float* __restrict__ W2,
                                               const float* __restrict__ W3,
                                               unsigned* __restrict__ wpk) {
    int y = blockIdx.y;
    const float* W = (y == 0) ? W1 : (y == 1) ? W2 : W3;
    unsigned* dh = wpk + (size_t)y * 16384;
    unsigned* dl = dh + 8192;
    int p = blockIdx.x * 256 + threadIdx.x;     // 0..8191
    int jp = p & 3;
    int l = (p >> 2) & 63;
    int st = p >> 8;                            // s*8 + t
    int s = st >> 3, t = st & 7;
    int k0 = ((l >> 4) << 3) + (jp << 1) + (s << 5);
    int n = (t << 4) + (l & 15);
    float x0 = W[k0 * 128 + n];
    float x1 = W[(k0 + 1) * 128 + n];
    unsigned hi, lo;
    split2(x0, x1, hi, lo);
    dh[p] = hi;
    dl[p] = lo;
}

// ---- MFMA GEMM: C[nrows,128] = A[nrows,128] @ W[128,128], split-bf16 emu ----
// A*W = Ah*Wh + Al*Wh + Ah*Wl (truncated splits; rel err ~2^-16).
// Block = 4 waves x 16 rows; each wave: 16x128 out = 8 col-tiles x 4 k-steps
// x 3 mfma. W frags staged to LDS (64 KB) once; A frags direct global.
__global__ __launch_bounds__(256) void k_gemm(const float* __restrict__ A,
                                              const unsigned* __restrict__ wsrc,
                                              float* __restrict__ C, int nrows) {
    __shared__ unsigned wlds[16384];            // hi[8192] then lo[8192]
    int tid = threadIdx.x;
    // stage W-pack (L2-resident source)
    uint4v* wl4 = (uint4v*)wlds;
    const uint4v* wg4 = (const uint4v*)wsrc;
#pragma unroll
    for (int i = 0; i < 16; ++i) wl4[tid + i * 256] = wg4[tid + i * 256];

    int w = tid >> 6, l = tid & 63;
    int m16 = l & 15, q = l >> 4;
    int rbase = blockIdx.x * 64 + w * 16;
    int row = rbase + m16;
    int rowc = row > nrows - 1 ? nrows - 1 : row;

    // A fragments: per k-step s, 8 floats A[row][s*32+q*8 .. +7] -> hi/lo bf16x8
    union u8 { unsigned u[4]; uint4v uv; short8 v; };
    u8 ah[4], al[4];
    const f4* A4 = (const f4*)A;
#pragma unroll
    for (int s = 0; s < 4; ++s) {
        f4 a0 = A4[(size_t)rowc * 32 + s * 8 + q * 2];
        f4 a1 = A4[(size_t)rowc * 32 + s * 8 + q * 2 + 1];
        split2(a0.x, a0.y, ah[s].u[0], al[s].u[0]);
        split2(a0.z, a0.w, ah[s].u[1], al[s].u[1]);
        split2(a1.x, a1.y, ah[s].u[2], al[s].u[2]);
        split2(a1.z, a1.w, ah[s].u[3], al[s].u[3]);
    }

    f4 acc[8];
#pragma unroll
    for (int t = 0; t < 8; ++t) acc[t] = (f4)0.0f;

    __syncthreads();

#pragma unroll 1
    for (int t = 0; t < 8; ++t) {
#pragma unroll
        for (int s = 0; s < 4; ++s) {
            int bi = ((s * 8 + t) * 64 + l) * 4;
            u8 bh, bl;
            bh.uv = *(const uint4v*)&wlds[bi];
            bl.uv = *(const uint4v*)&wlds[bi + 8192];
            acc[t] = __builtin_amdgcn_mfma_f32_16x16x32_bf16(ah[s].v, bh.v, acc[t], 0, 0, 0);
            acc[t] = __builtin_amdgcn_mfma_f32_16x16x32_bf16(al[s].v, bh.v, acc[t], 0, 0, 0);
            acc[t] = __builtin_amdgcn_mfma_f32_16x16x32_bf16(ah[s].v, bl.v, acc[t], 0, 0, 0);
        }
    }

    // D layout: col = lane&15, row = (lane>>4)*4 + reg
#pragma unroll
    for (int t = 0; t < 8; ++t) {
#pragma unroll
        for (int r = 0; r < 4; ++r) {
            int rr = rbase + q * 4 + r;
            if (rr < nrows) C[(size_t)rr * 128 + t * 16 + m16] = acc[t][r];
        }
    }
}

// ---- aggregation: 2 nodes per wave (half-wave = 32 lanes, lane = float4) ----
// out[n] = dinv[n]*( dinv[n]*h[n] + sum_s dinv[s]*h[s] ) + b
__global__ __launch_bounds__(256) void k_agg(const float* __restrict__ h,
                                             const int* __restrict__ rowptr,
                                             const int* __restrict__ cnt,
                                             const int* __restrict__ col,
                                             const float* __restrict__ dinv,
                                             const float* __restrict__ bias,
                                             float* __restrict__ out,
                                             float* __restrict__ out2, int relu) {
    int gw = (blockIdx.x * 256 + threadIdx.x) >> 6;
    int lane = threadIdx.x & 63;
    int half = lane >> 5;
    int sl = lane & 31;
    int n = gw * 2 + half;
    if (n >= NNODES) return;
    int beg = rowptr[n];
    int end = beg + cnt[n];
    float di = dinv[n];

    const f4* h4 = (const f4*)h;
    f4 a = di * h4[(size_t)n * 32 + sl];

    for (int base = beg; base < end; base += 32) {
        int rem = end - base;
        int cv = 0;
        float wv = 0.0f;
        if (sl < rem) {
            cv = col[base + sl];
            wv = dinv[cv];
        }
        int c = rem < 32 ? rem : 32;
        for (int j = 0; j < c; ++j) {
            int s = __shfl(cv, half * 32 + j);
            float wgt = __shfl(wv, half * 32 + j);
            a += wgt * h4[(size_t)s * 32 + sl];
        }
    }

    f4 bv = ((const f4*)bias)[sl];
    f4 o = di * a + bv;
    if (relu) {
        o.x = fmaxf(o.x, 0.0f);
        o.y = fmaxf(o.y, 0.0f);
        o.z = fmaxf(o.z, 0.0f);
        o.w = fmaxf(o.w, 0.0f);
    }
    ((f4*)out)[(size_t)n * 32 + sl] = o;
    if (out2) ((f4*)out2)[(size_t)n * 32 + sl] = o;
}

extern "C" void kernel_launch(void* const* d_in, const int* in_sizes, int n_in,
                              void* d_out, int out_size, void* d_ws, size_t ws_size,
                              hipStream_t stream) {
    const float* x  = (const float*)d_in[0];
    const int*   ei = (const int*)d_in[1];
    const float* W1 = (const float*)d_in[2];
    const float* b1 = (const float*)d_in[3];
    const float* W2 = (const float*)d_in[4];
    const float* b2 = (const float*)d_in[5];
    const float* W3 = (const float*)d_in[6];
    const float* b3 = (const float*)d_in[7];
    int E = in_sizes[1] / 2;
    const int* srcp = ei;
    const int* dstp = ei + E;
    float* outf = (float*)d_out;

    // workspace layout
    float*    bufA  = (float*)d_ws;                          // 25.6 MB
    int*      cnt   = (int*)(bufA + (size_t)NNODES * FDIM);  // N
    int*      fill  = cnt + NNODES;                          // N
    int*      total = fill + NNODES;                         // 1
    int*      rowptr= total + 1;                             // N
    float*    dinv  = (float*)(rowptr + NNODES);             // N
    int*      col   = (int*)(dinv + NNODES);                 // E
    unsigned* wpk   = (unsigned*)(col + E);                  // 3*16384 uints (192 KB)
    float*    bufB  = outf;  // first half of d_out doubles as ping-pong scratch

    (void)hipMemsetAsync(cnt, 0, sizeof(int) * (2 * NNODES + 1), stream);

    int eb = (E + 255) / 256;
    int nb = (NNODES + 255) / 256;
    k_prepw<<<dim3(32, 3), 256, 0, stream>>>(W1, W2, W3, wpk);
    k_count<<<eb, 256, 0, stream>>>(dstp, cnt, E);
    k_alloc<<<nb, 256, 0, stream>>>(cnt, rowptr, dinv, total, NNODES);
    k_fill<<<eb, 256, 0, stream>>>(srcp, dstp, rowptr, fill, col, E);

    int gb = (NNODES + 63) / 64;               // 782 GEMM blocks
    int ab = (NNODES / 2 * 64 + 255) / 256;    // 6250 agg blocks (2 nodes/wave)

    k_gemm<<<gb, 256, 0, stream>>>(x, wpk, bufA, NNODES);
    k_agg<<<ab, 256, 0, stream>>>(bufA, rowptr, cnt, col, dinv, b1, bufB, nullptr, 1);
    k_gemm<<<gb, 256, 0, stream>>>(bufB, wpk + 16384, bufA, NNODES);
    k_agg<<<ab, 256, 0, stream>>>(bufA, rowptr, cnt, col, dinv, b2, bufB, nullptr, 1);
    k_gemm<<<gb, 256, 0, stream>>>(bufB, wpk + 32768, bufA, NNODES);
    k_agg<<<ab, 256, 0, stream>>>(bufA, rowptr, cnt, col, dinv, b3, outf,
                                  outf + (size_t)NNODES * FDIM, 0);
}